// Round 1
// baseline (334.388 us; speedup 1.0000x reference)
//
#include <hip/hip_runtime.h>
#include <math.h>

// Shapes (fixed by the reference setup)
#define D 64
#define E 128
#define H 256
#define N 128
#define H2 512          // drive hidden + resistance hidden concatenated
#define SIXD 384

// ---------------- Workspace layout (floats) ----------------
// EV      [B][64]
// EVSUM   [B]
// E2      [B]
// SRC     [B][N][64]
// SRCT    [B][64][N]
// TGT     [B][N][64]
// VALS    [B][N][64]
// S2      [B][N]
// T2      [B][N]
// MU      [B][N]
// WA      [512][64]
// WB      [512][64]
// WE      [512][64]
// WG      [512]
// WBIAS   [512]
// ABUF    [B][N][512]
// BPT     [B][512][N]

// K0: effective weight matrices from dW1/rW1 and ln params
__global__ void k_effw(const float* __restrict__ dW1, const float* __restrict__ db1,
                       const float* __restrict__ rW1, const float* __restrict__ rb1,
                       const float* __restrict__ ln_g, const float* __restrict__ ln_b,
                       float* __restrict__ WA, float* __restrict__ WB,
                       float* __restrict__ WE, float* __restrict__ WG,
                       float* __restrict__ WBIAS) {
    int h = blockIdx.x;          // 0..511
    int d = threadIdx.x;         // 0..63
    const float* W1 = (h < H) ? (dW1 + h * SIXD) : (rW1 + (h - H) * SIXD);
    float b1 = (h < H) ? db1[h] : rb1[h - H];
    float gT = ln_g[d], gS = ln_g[64 + d], gE = ln_g[128 + d], gD = ln_g[192 + d];
    WA[h * 64 + d] = W1[d] * gT - W1[192 + d] * gD;          // coeff of tgt_i
    WB[h * 64 + d] = W1[64 + d] * gS + W1[192 + d] * gD;     // coeff of src_j
    WE[h * 64 + d] = W1[128 + d] * gE;                       // coeff of ev_b
    float sg = 0.f, sb = 0.f;
    #pragma unroll
    for (int c = 0; c < 6; ++c) {
        int k = c * 64 + d;
        sg += W1[k] * ln_g[k];
        sb += W1[k] * ln_b[k];
    }
    for (int o = 32; o > 0; o >>= 1) {
        sg += __shfl_down(sg, o);
        sb += __shfl_down(sb, o);
    }
    if (d == 0) { WG[h] = sg; WBIAS[h] = sb + b1; }
}

// K1: ev = event @ We.T + be, plus per-batch sums
__global__ void k_ev(const float* __restrict__ event, const float* __restrict__ We,
                     const float* __restrict__ be,
                     float* __restrict__ EV, float* __restrict__ EVSUM, float* __restrict__ E2) {
    int b = blockIdx.x, d = threadIdx.x;
    const float* evt = event + b * E;
    const float* w = We + d * E;
    float acc = be[d];
    for (int e = 0; e < E; ++e) acc += w[e] * evt[e];
    EV[b * 64 + d] = acc;
    float s = acc, s2 = acc * acc;
    for (int o = 32; o > 0; o >>= 1) {
        s  += __shfl_down(s, o);
        s2 += __shfl_down(s2, o);
    }
    if (d == 0) { EVSUM[b] = s; E2[b] = s2; }
}

// K2: src/tgt/values projections + per-slot stats
__global__ void k_proj(const float* __restrict__ x,
                       const float* __restrict__ Ws, const float* __restrict__ bs,
                       const float* __restrict__ Wt, const float* __restrict__ bt,
                       const float* __restrict__ Wv, const float* __restrict__ bv,
                       const float* __restrict__ EVSUM,
                       float* __restrict__ SRC, float* __restrict__ SRCT,
                       float* __restrict__ TGT, float* __restrict__ VALS,
                       float* __restrict__ S2, float* __restrict__ T2, float* __restrict__ MU) {
    int bn = blockIdx.x;
    int b = bn >> 7;
    int n = bn & (N - 1);
    int d = threadIdx.x;
    __shared__ float xl[64];
    xl[d] = x[bn * 64 + d];
    __syncthreads();
    float s = bs[d], t = bt[d], v = bv[d];
    for (int k = 0; k < 64; ++k) {
        float xv = xl[k];
        s += Ws[d * 64 + k] * xv;
        t += Wt[d * 64 + k] * xv;
        v += Wv[d * 64 + k] * xv;
    }
    SRC[bn * 64 + d] = s;
    SRCT[(b * 64 + d) * N + n] = s;
    TGT[bn * 64 + d] = t;
    VALS[bn * 64 + d] = v;
    float ssum = s, ssq = s * s, tsq = t * t;
    for (int o = 32; o > 0; o >>= 1) {
        ssum += __shfl_down(ssum, o);
        ssq  += __shfl_down(ssq, o);
        tsq  += __shfl_down(tsq, o);
    }
    if (d == 0) {
        S2[bn] = ssq;
        T2[bn] = tsq;
        MU[bn] = (2.f * ssum + EVSUM[b]) * (1.f / (float)SIXD);
    }
}

// K3: A[b,i,h] and B'[b,j,h] (stored transposed as BPT[b,h,j])
__global__ void k_ab(const float* __restrict__ SRC, const float* __restrict__ TGT,
                     const float* __restrict__ EV, const float* __restrict__ MU,
                     const float* __restrict__ WA, const float* __restrict__ WB,
                     const float* __restrict__ WE, const float* __restrict__ WG,
                     float* __restrict__ ABUF, float* __restrict__ BPT) {
    int bn = blockIdx.x;
    int b = bn >> 7;
    int n = bn & (N - 1);
    int t = threadIdx.x;   // 0..255
    __shared__ float sl[64], tl[64], el[64];
    if (t < 64) { sl[t] = SRC[bn * 64 + t]; tl[t] = TGT[bn * 64 + t]; el[t] = EV[b * 64 + t]; }
    __syncthreads();
    float mu = MU[bn];
    for (int h = t; h < H2; h += 256) {
        const float* wa = WA + h * 64;
        const float* wb = WB + h * 64;
        const float* we = WE + h * 64;
        float a = 0.f, bb = 0.f, c = 0.f;
        #pragma unroll 8
        for (int d = 0; d < 64; ++d) {
            a  += wa[d] * tl[d];
            bb += wb[d] * sl[d];
            c  += we[d] * el[d];
        }
        ABUF[bn * H2 + h] = a;
        BPT[(b * H2 + h) * N + n] = bb + c - mu * WG[h];
    }
}

// K4: main per-pair kernel. Block = (b,i), thread = j.
__launch_bounds__(128)
__global__ void k_main(const float* __restrict__ SRCT, const float* __restrict__ TGT,
                       const float* __restrict__ VALS,
                       const float* __restrict__ S2, const float* __restrict__ T2,
                       const float* __restrict__ E2, const float* __restrict__ MU,
                       const float* __restrict__ ABUF, const float* __restrict__ BPT,
                       const float* __restrict__ WBIAS,
                       const float* __restrict__ dW2, const float* __restrict__ db2,
                       const float* __restrict__ rW2, const float* __restrict__ rb2,
                       const float* __restrict__ gate_bias,
                       float* __restrict__ out) {
    int bn = blockIdx.x;
    int b = bn >> 7;
    int i = bn & (N - 1);
    int j = threadIdx.x;   // 0..127
    __shared__ float Al[H2], wbl[H2], w2l[H2], tl[64], gl[N];
    for (int h = j; h < H2; h += 128) {
        Al[h]  = ABUF[bn * H2 + h];
        wbl[h] = WBIAS[h];
        w2l[h] = (h < H) ? dW2[h] : rW2[h - H];
    }
    if (j < 64) tl[j] = TGT[bn * 64 + j];
    __syncthreads();

    // src_j . tgt_i
    const float* st = SRCT + b * 64 * N;
    float dot = 0.f;
    #pragma unroll 8
    for (int d = 0; d < 64; ++d) dot += st[d * N + j] * tl[d];

    float muj = MU[b * N + j];
    float meansq = (2.f * T2[bn] + 2.f * S2[b * N + j] - 2.f * dot + E2[b]) * (1.f / (float)SIXD);
    float var = meansq - muj * muj;
    float inv_std = rsqrtf(var + 1e-5f);

    const float* Bp = BPT + b * H2 * N + j;
    float drive = 0.f, resist = 0.f;
    #pragma unroll 4
    for (int h = 0; h < H; ++h) {
        float pre = inv_std * (Al[h] + Bp[h * N]) + wbl[h];
        float g = 0.5f * pre * (1.f + erff(pre * 0.70710678118654752f));
        drive += g * w2l[h];
    }
    #pragma unroll 4
    for (int h = H; h < H2; ++h) {
        float pre = inv_std * (Al[h] + Bp[h * N]) + wbl[h];
        float g = 0.5f * pre * (1.f + erff(pre * 0.70710678118654752f));
        resist += g * w2l[h];
    }
    drive += db2[0];
    resist += rb2[0];

    float sp = (resist > 20.f) ? resist : log1pf(expf(resist));
    float rpos = sp + 1e-6f;
    float energy = drive / rpos;
    energy = fminf(fmaxf(energy, -3.f), 3.f);
    float z = energy + gate_bias[0];
    float gate = 1.f / (1.f + expf(-z));
    if (j == i) gate = 0.f;
    gl[j] = gate;
    __syncthreads();

    if (j < 64) {
        float acc = 0.f, gm = 0.f;
        const float* v = VALS + b * N * 64 + j;   // stride 64 over jj, lane = d
        #pragma unroll 8
        for (int jj = 0; jj < N; ++jj) {
            float g = gl[jj];
            gm += g;
            acc += g * v[jj * 64];
        }
        gm = fmaxf(gm, 1e-6f);
        out[bn * 64 + j] = acc / gm;
    }
}

extern "C" void kernel_launch(void* const* d_in, const int* in_sizes, int n_in,
                              void* d_out, int out_size, void* d_ws, size_t ws_size,
                              hipStream_t stream) {
    const float* x        = (const float*)d_in[0];
    const float* event    = (const float*)d_in[1];
    const float* We       = (const float*)d_in[2];
    const float* be       = (const float*)d_in[3];
    const float* Ws       = (const float*)d_in[4];
    const float* bs       = (const float*)d_in[5];
    const float* Wt       = (const float*)d_in[6];
    const float* bt       = (const float*)d_in[7];
    const float* Wv       = (const float*)d_in[8];
    const float* bv       = (const float*)d_in[9];
    const float* ln_g     = (const float*)d_in[10];
    const float* ln_b     = (const float*)d_in[11];
    const float* dW1      = (const float*)d_in[12];
    const float* db1      = (const float*)d_in[13];
    const float* dW2      = (const float*)d_in[14];
    const float* db2      = (const float*)d_in[15];
    const float* rW1      = (const float*)d_in[16];
    const float* rb1      = (const float*)d_in[17];
    const float* rW2      = (const float*)d_in[18];
    const float* rb2      = (const float*)d_in[19];
    const float* gate_b   = (const float*)d_in[20];

    const int B = in_sizes[0] / (N * D);   // 8

    float* ws = (float*)d_ws;
    float* EV    = ws;             ws += B * 64;
    float* EVSUM = ws;             ws += B;
    float* E2    = ws;             ws += B;
    float* SRC   = ws;             ws += B * N * 64;
    float* SRCT  = ws;             ws += B * 64 * N;
    float* TGT   = ws;             ws += B * N * 64;
    float* VALS  = ws;             ws += B * N * 64;
    float* S2    = ws;             ws += B * N;
    float* T2    = ws;             ws += B * N;
    float* MU    = ws;             ws += B * N;
    float* WA    = ws;             ws += H2 * 64;
    float* WB    = ws;             ws += H2 * 64;
    float* WE    = ws;             ws += H2 * 64;
    float* WG    = ws;             ws += H2;
    float* WBIAS = ws;             ws += H2;
    float* ABUF  = ws;             ws += B * N * H2;
    float* BPT   = ws;             ws += B * H2 * N;

    hipLaunchKernelGGL(k_effw, dim3(H2), dim3(64), 0, stream,
                       dW1, db1, rW1, rb1, ln_g, ln_b, WA, WB, WE, WG, WBIAS);
    hipLaunchKernelGGL(k_ev, dim3(B), dim3(64), 0, stream,
                       event, We, be, EV, EVSUM, E2);
    hipLaunchKernelGGL(k_proj, dim3(B * N), dim3(64), 0, stream,
                       x, Ws, bs, Wt, bt, Wv, bv, EVSUM,
                       SRC, SRCT, TGT, VALS, S2, T2, MU);
    hipLaunchKernelGGL(k_ab, dim3(B * N), dim3(256), 0, stream,
                       SRC, TGT, EV, MU, WA, WB, WE, WG, ABUF, BPT);
    hipLaunchKernelGGL(k_main, dim3(B * N), dim3(128), 0, stream,
                       SRCT, TGT, VALS, S2, T2, E2, MU, ABUF, BPT, WBIAS,
                       dW2, db2, rW2, rb2, gate_b, (float*)d_out);
}

// Round 3
// 203.284 us; speedup vs baseline: 1.6449x; 1.6449x over previous
//
#include <hip/hip_runtime.h>
#include <math.h>

// Shapes (fixed by the reference setup)
#define D 64
#define E 128
#define H 256
#define N 128
#define H2 512          // drive hidden + resistance hidden concatenated
#define SIXD 384

// ---------------- Workspace layout (floats) ----------------
// EV      [B][64]
// EVSUM   [B]
// E2      [B]
// SRCT    [B][64][N]
// TGT     [B][N][64]
// VALS    [B][N][64]
// S2      [B][N]
// T2      [B][N]
// MU      [B][N]
// WAT     [64][512]   (transposed effective weights, coeff of tgt_i)
// WBT     [64][512]   (coeff of src_j)
// WET     [64][512]   (coeff of ev_b)
// WG      [512]
// WBIAS   [512]
// ABUF    [B][N][512]
// BPT     [B][512][N]

// K1: fused {effective-weight precompute} + {event projection}
__global__ void k_pre(const float* __restrict__ dW1, const float* __restrict__ db1,
                      const float* __restrict__ rW1, const float* __restrict__ rb1,
                      const float* __restrict__ ln_g, const float* __restrict__ ln_b,
                      const float* __restrict__ event, const float* __restrict__ We,
                      const float* __restrict__ be,
                      float* __restrict__ WAT, float* __restrict__ WBT,
                      float* __restrict__ WET, float* __restrict__ WG,
                      float* __restrict__ WBIAS,
                      float* __restrict__ EV, float* __restrict__ EVSUM,
                      float* __restrict__ E2) {
    int bid = blockIdx.x;
    int d = threadIdx.x;         // 0..63
    if (bid < H2) {
        int h = bid;
        const float* W1 = (h < H) ? (dW1 + h * SIXD) : (rW1 + (h - H) * SIXD);
        float b1 = (h < H) ? db1[h] : rb1[h - H];
        float gT = ln_g[d], gS = ln_g[64 + d], gE = ln_g[128 + d], gD = ln_g[192 + d];
        WAT[d * H2 + h] = W1[d] * gT - W1[192 + d] * gD;          // coeff of tgt_i
        WBT[d * H2 + h] = W1[64 + d] * gS + W1[192 + d] * gD;     // coeff of src_j
        WET[d * H2 + h] = W1[128 + d] * gE;                       // coeff of ev_b
        float sg = 0.f, sb = 0.f;
        #pragma unroll
        for (int c = 0; c < 6; ++c) {
            int k = c * 64 + d;
            sg += W1[k] * ln_g[k];
            sb += W1[k] * ln_b[k];
        }
        for (int o = 32; o > 0; o >>= 1) {
            sg += __shfl_down(sg, o);
            sb += __shfl_down(sb, o);
        }
        if (d == 0) { WG[h] = sg; WBIAS[h] = sb + b1; }
    } else {
        int b = bid - H2;
        const float* evt = event + b * E;
        const float* w = We + d * E;
        float acc = be[d];
        for (int e = 0; e < E; ++e) acc += w[e] * evt[e];
        EV[b * 64 + d] = acc;
        float s = acc, s2 = acc * acc;
        for (int o = 32; o > 0; o >>= 1) {
            s  += __shfl_down(s, o);
            s2 += __shfl_down(s2, o);
        }
        if (d == 0) { EVSUM[b] = s; E2[b] = s2; }
    }
}

// K2: fused {src/tgt/val projections + per-slot stats} + {A,B' hidden precompute}
__launch_bounds__(256)
__global__ void k_projab(const float* __restrict__ x,
                         const float* __restrict__ Ws, const float* __restrict__ bs,
                         const float* __restrict__ Wt, const float* __restrict__ bt,
                         const float* __restrict__ Wv, const float* __restrict__ bv,
                         const float* __restrict__ EV, const float* __restrict__ EVSUM,
                         const float* __restrict__ WAT, const float* __restrict__ WBT,
                         const float* __restrict__ WET, const float* __restrict__ WG,
                         float* __restrict__ SRCT, float* __restrict__ TGT,
                         float* __restrict__ VALS,
                         float* __restrict__ S2, float* __restrict__ T2,
                         float* __restrict__ MU,
                         float* __restrict__ ABUF, float* __restrict__ BPT) {
    int bn = blockIdx.x;
    int b = bn >> 7;
    int n = bn & (N - 1);
    int tid = threadIdx.x;       // 0..255
    int r = tid >> 6;            // 0..3
    int d = tid & 63;
    __shared__ float xl[64], sl[64], tl[64], el[64];
    __shared__ float mus;
    if (tid < 64) xl[tid] = x[bn * 64 + tid];
    else if (tid < 128) el[d] = EV[b * 64 + d];
    __syncthreads();
    if (r == 0) {
        float s = bs[d];
        for (int k = 0; k < 64; ++k) s += Ws[d * 64 + k] * xl[k];
        sl[d] = s;
        SRCT[(b * 64 + d) * N + n] = s;
        float ssum = s, ssq = s * s;
        for (int o = 32; o > 0; o >>= 1) {
            ssum += __shfl_down(ssum, o);
            ssq  += __shfl_down(ssq, o);
        }
        if (d == 0) {
            S2[bn] = ssq;
            float mu = (2.f * ssum + EVSUM[b]) * (1.f / (float)SIXD);
            MU[bn] = mu;
            mus = mu;
        }
    } else if (r == 1) {
        float t = bt[d];
        for (int k = 0; k < 64; ++k) t += Wt[d * 64 + k] * xl[k];
        tl[d] = t;
        TGT[bn * 64 + d] = t;
        float tsq = t * t;
        for (int o = 32; o > 0; o >>= 1) tsq += __shfl_down(tsq, o);
        if (d == 0) T2[bn] = tsq;
    } else if (r == 2) {
        float v = bv[d];
        for (int k = 0; k < 64; ++k) v += Wv[d * 64 + k] * xl[k];
        VALS[bn * 64 + d] = v;
    }
    __syncthreads();
    float mu = mus;
    for (int h = tid; h < H2; h += 256) {
        float a = 0.f, bb = 0.f, c = 0.f;
        #pragma unroll 8
        for (int k = 0; k < 64; ++k) {
            a  += WAT[k * H2 + h] * tl[k];
            bb += WBT[k * H2 + h] * sl[k];
            c  += WET[k * H2 + h] * el[k];
        }
        ABUF[bn * H2 + h] = a;
        BPT[(b * H2 + h) * N + n] = bb + c - mu * WG[h];
    }
}

// K3: main per-pair kernel. Block = (b,i), 512 threads: q = h-quarter, j = source slot.
__launch_bounds__(512)
__global__ void k_main(const float* __restrict__ SRCT, const float* __restrict__ TGT,
                       const float* __restrict__ VALS,
                       const float* __restrict__ S2, const float* __restrict__ T2,
                       const float* __restrict__ E2, const float* __restrict__ MU,
                       const float* __restrict__ ABUF, const float* __restrict__ BPT,
                       const float* __restrict__ WBIAS,
                       const float* __restrict__ dW2, const float* __restrict__ db2,
                       const float* __restrict__ rW2, const float* __restrict__ rb2,
                       const float* __restrict__ gate_bias,
                       float* __restrict__ out) {
    int bn = blockIdx.x;
    int b = bn >> 7;
    int i = bn & (N - 1);
    int tid = threadIdx.x;       // 0..511
    int q = tid >> 7;            // 0..3  (h-quarter)
    int j = tid & (N - 1);       // 0..127
    __shared__ float Al[H2], wbl[H2], w2l[H2], tl[64], part[512], gl[N];
    __shared__ float accp[512], gmp[8];
    Al[tid]  = ABUF[bn * H2 + tid];
    wbl[tid] = WBIAS[tid];
    w2l[tid] = (tid < H) ? dW2[tid] : rW2[tid - H];
    if (tid < 64) tl[tid] = TGT[bn * 64 + tid];
    __syncthreads();

    // src_j . tgt_i   (redundant across q; only 64 iterations, L1-resident)
    const float* st = SRCT + b * 64 * N;
    float dot = 0.f;
    #pragma unroll 8
    for (int dd = 0; dd < 64; ++dd) dot += st[dd * N + j] * tl[dd];

    float muj = MU[b * N + j];
    float meansq = (2.f * T2[bn] + 2.f * S2[b * N + j] - 2.f * dot + E2[b]) * (1.f / (float)SIXD);
    float inv_std = rsqrtf(meansq - muj * muj + 1e-5f);

    const float* Bp = BPT + (b * H2 + q * 128) * N + j;
    int hbase = q * 128;
    float acc = 0.f;
    #pragma unroll 8
    for (int hh = 0; hh < 128; ++hh) {
        int h = hbase + hh;
        float pre = inv_std * (Al[h] + Bp[hh * N]) + wbl[h];
        float g = 0.5f * pre * (1.f + erff(pre * 0.70710678118654752f));
        acc += g * w2l[h];
    }
    part[q * 128 + j] = acc;
    __syncthreads();

    if (tid < N) {
        float drive  = part[j] + part[128 + j] + db2[0];
        float resist = part[256 + j] + part[384 + j] + rb2[0];
        float sp = (resist > 20.f) ? resist : log1pf(expf(resist));
        float energy = drive / (sp + 1e-6f);
        energy = fminf(fmaxf(energy, -3.f), 3.f);
        float gate = 1.f / (1.f + expf(-(energy + gate_bias[0])));
        if (j == i) gate = 0.f;
        gl[j] = gate;
    }
    __syncthreads();

    // aggregation: p = j-chunk (8 chunks of 16), dd = output dim
    int p = tid >> 6;            // 0..7
    int dd = tid & 63;
    float va = 0.f, gm = 0.f;
    const float* v = VALS + b * N * 64 + dd;
    #pragma unroll
    for (int jj = p * 16; jj < p * 16 + 16; ++jj) {
        float g = gl[jj];
        gm += g;
        va += g * v[jj * 64];
    }
    accp[p * 64 + dd] = va;
    if (dd == 0) gmp[p] = gm;
    __syncthreads();

    if (tid < 64) {
        float sum = 0.f, gmsum = 0.f;
        #pragma unroll
        for (int pp = 0; pp < 8; ++pp) {
            sum += accp[pp * 64 + tid];
            gmsum += gmp[pp];
        }
        gmsum = fmaxf(gmsum, 1e-6f);
        out[bn * 64 + tid] = sum / gmsum;
    }
}

extern "C" void kernel_launch(void* const* d_in, const int* in_sizes, int n_in,
                              void* d_out, int out_size, void* d_ws, size_t ws_size,
                              hipStream_t stream) {
    const float* x        = (const float*)d_in[0];
    const float* event    = (const float*)d_in[1];
    const float* We       = (const float*)d_in[2];
    const float* be       = (const float*)d_in[3];
    const float* Ws       = (const float*)d_in[4];
    const float* bs       = (const float*)d_in[5];
    const float* Wt       = (const float*)d_in[6];
    const float* bt       = (const float*)d_in[7];
    const float* Wv       = (const float*)d_in[8];
    const float* bv       = (const float*)d_in[9];
    const float* ln_g     = (const float*)d_in[10];
    const float* ln_b     = (const float*)d_in[11];
    const float* dW1      = (const float*)d_in[12];
    const float* db1      = (const float*)d_in[13];
    const float* dW2      = (const float*)d_in[14];
    const float* db2      = (const float*)d_in[15];
    const float* rW1      = (const float*)d_in[16];
    const float* rb1      = (const float*)d_in[17];
    const float* rW2      = (const float*)d_in[18];
    const float* rb2      = (const float*)d_in[19];
    const float* gate_b   = (const float*)d_in[20];

    const int B = in_sizes[0] / (N * D);   // 8

    float* ws = (float*)d_ws;
    float* EV    = ws;             ws += B * 64;
    float* EVSUM = ws;             ws += B;
    float* E2    = ws;             ws += B;
    float* SRCT  = ws;             ws += B * 64 * N;
    float* TGT   = ws;             ws += B * N * 64;
    float* VALS  = ws;             ws += B * N * 64;
    float* S2    = ws;             ws += B * N;
    float* T2    = ws;             ws += B * N;
    float* MU    = ws;             ws += B * N;
    float* WAT   = ws;             ws += 64 * H2;
    float* WBT   = ws;             ws += 64 * H2;
    float* WET   = ws;             ws += 64 * H2;
    float* WG    = ws;             ws += H2;
    float* WBIAS = ws;             ws += H2;
    float* ABUF  = ws;             ws += B * N * H2;
    float* BPT   = ws;             ws += B * H2 * N;

    hipLaunchKernelGGL(k_pre, dim3(H2 + B), dim3(64), 0, stream,
                       dW1, db1, rW1, rb1, ln_g, ln_b, event, We, be,
                       WAT, WBT, WET, WG, WBIAS, EV, EVSUM, E2);
    hipLaunchKernelGGL(k_projab, dim3(B * N), dim3(256), 0, stream,
                       x, Ws, bs, Wt, bt, Wv, bv, EV, EVSUM,
                       WAT, WBT, WET, WG,
                       SRCT, TGT, VALS, S2, T2, MU, ABUF, BPT);
    hipLaunchKernelGGL(k_main, dim3(B * N), dim3(512), 0, stream,
                       SRCT, TGT, VALS, S2, T2, E2, MU, ABUF, BPT, WBIAS,
                       dW2, db2, rW2, rb2, gate_b, (float*)d_out);
}

// Round 4
// 165.813 us; speedup vs baseline: 2.0167x; 1.2260x over previous
//
#include <hip/hip_runtime.h>
#include <math.h>

// Shapes (fixed by the reference setup)
#define D 64
#define E 128
#define H 256
#define N 128
#define H2 512          // drive hidden + resistance hidden concatenated
#define SIXD 384
#define INV_SIXD 0.0026041666666666665f

// ---------------- Workspace layout (floats) ----------------
// EVSUM  [B]
// E2     [B]
// SRCT   [B][64][N]
// TGT    [B][N][64]
// VALS   [B][N][64]
// S2     [B][N]
// T2     [B][N]
// MU     [B][N]
// WAT    [64][512]    coeff of tgt_i (transposed: k-major)
// WBT    [64][512]    coeff of src_j
// WG     [512]
// WBIAS  [512]
// EVH    [B][512]     event contribution to hidden pre-activation
// WsT/WtT/WvT [64][64] transposed projection weights
// ABUF   [B][N][512]
// BPT    [B][512][N]

__device__ __forceinline__ float fast_erff(float x) {
    float ax = fabsf(x);
    float t = __builtin_amdgcn_rcpf(fmaf(0.3275911f, ax, 1.0f));
    float p = t * fmaf(t, fmaf(t, fmaf(t, fmaf(t, 1.061405429f, -1.453152027f),
                               1.421413741f), -0.284496736f), 0.254829592f);
    float r = fmaf(-p, __expf(-ax * ax), 1.0f);
    return copysignf(r, x);
}

__device__ __forceinline__ float fast_gelu(float x) {
    return 0.5f * x * (1.0f + fast_erff(x * 0.70710678118654752f));
}

// K1: all input-only precompute (roles by blockIdx)
__global__ void k_prep(const float* __restrict__ dW1, const float* __restrict__ db1,
                       const float* __restrict__ rW1, const float* __restrict__ rb1,
                       const float* __restrict__ ln_g, const float* __restrict__ ln_b,
                       const float* __restrict__ event, const float* __restrict__ We,
                       const float* __restrict__ be,
                       const float* __restrict__ Ws, const float* __restrict__ Wt,
                       const float* __restrict__ Wv,
                       float* __restrict__ WAT, float* __restrict__ WBT,
                       float* __restrict__ WG, float* __restrict__ WBIAS,
                       float* __restrict__ EVH,
                       float* __restrict__ EVSUM, float* __restrict__ E2,
                       float* __restrict__ WsT, float* __restrict__ WtT,
                       float* __restrict__ WvT, int B) {
    int bid = blockIdx.x;
    int tid = threadIdx.x;       // 0..255
    if (bid < 64) {
        // effective-weight transpose: one d per block, lanes over h (coalesced writes)
        int d = bid;
        float gT = ln_g[d], gS = ln_g[64 + d], gD = ln_g[192 + d];
        for (int h = tid; h < H2; h += 256) {
            const float* W1 = (h < H) ? (dW1 + h * SIXD) : (rW1 + (h - H) * SIXD);
            float w3 = W1[192 + d];
            WAT[d * H2 + h] = W1[d] * gT - w3 * gD;
            WBT[d * H2 + h] = W1[64 + d] * gS + w3 * gD;
        }
    } else if (bid < 66) {
        // WG / WBIAS: one h per thread
        int h = (bid - 64) * 256 + tid;
        const float* W1 = (h < H) ? (dW1 + h * SIXD) : (rW1 + (h - H) * SIXD);
        float b1 = (h < H) ? db1[h] : rb1[h - H];
        float sg = 0.f, sb = 0.f;
        for (int m = 0; m < SIXD; ++m) {
            float w = W1[m];
            sg = fmaf(w, ln_g[m], sg);
            sb = fmaf(w, ln_b[m], sb);
        }
        WG[h] = sg;
        WBIAS[h] = sb + b1;
    } else if (bid < 66 + 2 * B) {
        // event projection + EVH
        int t = bid - 66;
        int b = t >> 1, half = t & 1;
        __shared__ float egl[64];
        if (tid < 64) {
            int k = tid;
            float acc = be[k];
            const float* evt = event + b * E;
            const float* w = We + k * E;
            for (int e = 0; e < E; ++e) acc = fmaf(w[e], evt[e], acc);
            egl[k] = acc * ln_g[128 + k];
            if (half == 0) {
                float s = acc, s2 = acc * acc;
                for (int o = 32; o > 0; o >>= 1) {
                    s  += __shfl_down(s, o);
                    s2 += __shfl_down(s2, o);
                }
                if (k == 0) { EVSUM[b] = s; E2[b] = s2; }
            }
        }
        __syncthreads();
        int h = half * 256 + tid;
        const float* W1 = (h < H) ? (dW1 + h * SIXD) : (rW1 + (h - H) * SIXD);
        float acc = 0.f;
        #pragma unroll 8
        for (int k = 0; k < 64; ++k) acc = fmaf(W1[128 + k], egl[k], acc);
        EVH[b * H2 + h] = acc;
    } else {
        // transpose Ws/Wt/Wv -> WsT/WtT/WvT  (WT[k][d] = W[d][k])
        int m = bid - (66 + 2 * B);
        const float* W = (m == 0) ? Ws : (m == 1) ? Wt : Wv;
        float* WT = (m == 0) ? WsT : (m == 1) ? WtT : WvT;
        for (int idx = tid; idx < 64 * 64; idx += 256) {
            int d = idx >> 6, k = idx & 63;
            WT[k * 64 + d] = W[idx];
        }
    }
}

// K2: projections + stats + A,B' hidden precompute. Block = (b, n-pair), 512 threads.
__launch_bounds__(512)
__global__ void k_projab(const float* __restrict__ x,
                         const float* __restrict__ WsT, const float* __restrict__ bs,
                         const float* __restrict__ WtT, const float* __restrict__ bt,
                         const float* __restrict__ WvT, const float* __restrict__ bv,
                         const float* __restrict__ EVSUM,
                         const float* __restrict__ WAT, const float* __restrict__ WBT,
                         const float* __restrict__ WG, const float* __restrict__ EVH,
                         float* __restrict__ SRCT, float* __restrict__ TGT,
                         float* __restrict__ VALS,
                         float* __restrict__ S2, float* __restrict__ T2,
                         float* __restrict__ MU,
                         float* __restrict__ ABUF, float* __restrict__ BPT) {
    int bn2 = blockIdx.x;
    int b = bn2 >> 6;
    int np = bn2 & 63;
    int n0 = np * 2, n1 = n0 + 1;
    int tid = threadIdx.x;       // 0..511
    int q = tid >> 6;            // 0..7
    int d = tid & 63;
    __shared__ float xl0[64], xl1[64], sl0[64], sl1[64], tl0[64], tl1[64];
    __shared__ float mus[2];
    if (q == 0) xl0[d] = x[(b * N + n0) * 64 + d];
    else if (q == 1) xl1[d] = x[(b * N + n1) * 64 + d];
    __syncthreads();

    if (q < 6) {
        int which = (q < 3) ? 0 : 1;             // n0 or n1
        int role = (q < 3) ? q : q - 3;          // 0=src 1=tgt 2=val
        const float* xl = which ? xl1 : xl0;
        int n = which ? n1 : n0;
        const float* WT = (role == 0) ? WsT : (role == 1) ? WtT : WvT;
        float bias = (role == 0) ? bs[d] : (role == 1) ? bt[d] : bv[d];
        float acc = bias;
        #pragma unroll 8
        for (int k = 0; k < 64; ++k) acc = fmaf(WT[k * 64 + d], xl[k], acc);
        if (role == 0) {
            (which ? sl1 : sl0)[d] = acc;
            SRCT[(b * 64 + d) * N + n] = acc;
            float ssum = acc, ssq = acc * acc;
            for (int o = 32; o > 0; o >>= 1) {
                ssum += __shfl_down(ssum, o);
                ssq  += __shfl_down(ssq, o);
            }
            if (d == 0) {
                S2[b * N + n] = ssq;
                float mu = (2.f * ssum + EVSUM[b]) * INV_SIXD;
                MU[b * N + n] = mu;
                mus[which] = mu;
            }
        } else if (role == 1) {
            (which ? tl1 : tl0)[d] = acc;
            TGT[(b * N + n) * 64 + d] = acc;
            float tsq = acc * acc;
            for (int o = 32; o > 0; o >>= 1) tsq += __shfl_down(tsq, o);
            if (d == 0) T2[b * N + n] = tsq;
        } else {
            VALS[(b * N + n) * 64 + d] = acc;
        }
    }
    __syncthreads();

    int h = tid;                 // one h per thread
    float a0 = 0.f, a1 = 0.f, b0 = 0.f, b1 = 0.f;
    #pragma unroll 8
    for (int k = 0; k < 64; ++k) {
        float wa = WAT[k * H2 + h];
        float wb = WBT[k * H2 + h];
        a0 = fmaf(wa, tl0[k], a0);
        a1 = fmaf(wa, tl1[k], a1);
        b0 = fmaf(wb, sl0[k], b0);
        b1 = fmaf(wb, sl1[k], b1);
    }
    float evh = EVH[b * H2 + h];
    float wg = WG[h];
    ABUF[(b * N + n0) * H2 + h] = a0;
    ABUF[(b * N + n1) * H2 + h] = a1;
    BPT[(b * H2 + h) * N + n0] = b0 + evh - mus[0] * wg;
    BPT[(b * H2 + h) * N + n1] = b1 + evh - mus[1] * wg;
}

// K3: main per-pair kernel. Block = (b,i), 512 threads: q = h-eighth, p = j-pair.
__launch_bounds__(512)
__global__ void k_main(const float* __restrict__ SRCT, const float* __restrict__ TGT,
                       const float* __restrict__ VALS,
                       const float* __restrict__ S2, const float* __restrict__ T2,
                       const float* __restrict__ E2, const float* __restrict__ MU,
                       const float* __restrict__ ABUF, const float* __restrict__ BPT,
                       const float* __restrict__ WBIAS,
                       const float* __restrict__ dW2, const float* __restrict__ db2,
                       const float* __restrict__ rW2, const float* __restrict__ rb2,
                       const float* __restrict__ gate_bias,
                       float* __restrict__ out) {
    int bn = blockIdx.x;
    int b = bn >> 7;
    int i = bn & (N - 1);
    int tid = threadIdx.x;       // 0..511
    int q = tid >> 6;            // 0..7  (64-h chunk)
    int p = tid & 63;            // j-pair: j0=2p, j1=2p+1
    __shared__ float Al[H2], wbl[H2], w2l[H2], tl[64], part[8 * N], gl[N];
    __shared__ float accp[512], gmp[8];
    Al[tid]  = ABUF[bn * H2 + tid];
    wbl[tid] = WBIAS[tid];
    w2l[tid] = (tid < H) ? dW2[tid] : rW2[tid - H];
    if (tid < 64) tl[tid] = TGT[bn * 64 + tid];
    __syncthreads();

    // dots src_j . tgt_i for both j of the pair
    const float* st = SRCT + b * 64 * N;
    float d0 = 0.f, d1 = 0.f;
    #pragma unroll 8
    for (int dd = 0; dd < 64; ++dd) {
        float2 sv = *(const float2*)&st[dd * N + 2 * p];
        float t = tl[dd];
        d0 = fmaf(sv.x, t, d0);
        d1 = fmaf(sv.y, t, d1);
    }
    float2 muv = *(const float2*)&MU[b * N + 2 * p];
    float2 s2v = *(const float2*)&S2[b * N + 2 * p];
    float t2 = T2[bn], e2 = E2[b];
    float ms0 = (2.f * t2 + 2.f * s2v.x - 2.f * d0 + e2) * INV_SIXD;
    float ms1 = (2.f * t2 + 2.f * s2v.y - 2.f * d1 + e2) * INV_SIXD;
    float inv0 = rsqrtf(ms0 - muv.x * muv.x + 1e-5f);
    float inv1 = rsqrtf(ms1 - muv.y * muv.y + 1e-5f);

    const float* Bp = BPT + (b * H2 + q * 64) * N + 2 * p;
    int hbase = q * 64;
    float acc0 = 0.f, acc1 = 0.f;
    #pragma unroll 4
    for (int hh = 0; hh < 64; ++hh) {
        int h = hbase + hh;
        float2 bp = *(const float2*)&Bp[hh * N];
        float al = Al[h], wb = wbl[h], w2 = w2l[h];
        float pre0 = fmaf(inv0, al + bp.x, wb);
        float pre1 = fmaf(inv1, al + bp.y, wb);
        acc0 = fmaf(fast_gelu(pre0), w2, acc0);
        acc1 = fmaf(fast_gelu(pre1), w2, acc1);
    }
    part[q * N + 2 * p] = acc0;
    part[q * N + 2 * p + 1] = acc1;
    __syncthreads();

    if (tid < N) {
        int j = tid;
        float drive  = part[j] + part[N + j] + part[2 * N + j] + part[3 * N + j] + db2[0];
        float resist = part[4 * N + j] + part[5 * N + j] + part[6 * N + j] + part[7 * N + j] + rb2[0];
        float sp = (resist > 20.f) ? resist : __logf(1.f + __expf(resist));
        float energy = drive / (sp + 1e-6f);
        energy = fminf(fmaxf(energy, -3.f), 3.f);
        float gate = __builtin_amdgcn_rcpf(1.f + __expf(-(energy + gate_bias[0])));
        if (j == i) gate = 0.f;
        gl[j] = gate;
    }
    __syncthreads();

    // aggregation: pc = j-chunk (8 chunks of 16), dd = output dim
    int pc = tid >> 6;           // 0..7
    int dd = tid & 63;
    float va = 0.f, gm = 0.f;
    const float* v = VALS + b * N * 64 + dd;
    #pragma unroll
    for (int jj = pc * 16; jj < pc * 16 + 16; ++jj) {
        float g = gl[jj];
        gm += g;
        va = fmaf(g, v[jj * 64], va);
    }
    accp[pc * 64 + dd] = va;
    if (dd == 0) gmp[pc] = gm;
    __syncthreads();

    if (tid < 64) {
        float sum = 0.f, gmsum = 0.f;
        #pragma unroll
        for (int pp = 0; pp < 8; ++pp) {
            sum += accp[pp * 64 + tid];
            gmsum += gmp[pp];
        }
        gmsum = fmaxf(gmsum, 1e-6f);
        out[bn * 64 + tid] = sum / gmsum;
    }
}

extern "C" void kernel_launch(void* const* d_in, const int* in_sizes, int n_in,
                              void* d_out, int out_size, void* d_ws, size_t ws_size,
                              hipStream_t stream) {
    const float* x        = (const float*)d_in[0];
    const float* event    = (const float*)d_in[1];
    const float* We       = (const float*)d_in[2];
    const float* be       = (const float*)d_in[3];
    const float* Ws       = (const float*)d_in[4];
    const float* bs       = (const float*)d_in[5];
    const float* Wt       = (const float*)d_in[6];
    const float* bt       = (const float*)d_in[7];
    const float* Wv       = (const float*)d_in[8];
    const float* bv       = (const float*)d_in[9];
    const float* ln_g     = (const float*)d_in[10];
    const float* ln_b     = (const float*)d_in[11];
    const float* dW1      = (const float*)d_in[12];
    const float* db1      = (const float*)d_in[13];
    const float* dW2      = (const float*)d_in[14];
    const float* db2      = (const float*)d_in[15];
    const float* rW1      = (const float*)d_in[16];
    const float* rb1      = (const float*)d_in[17];
    const float* rW2      = (const float*)d_in[18];
    const float* rb2      = (const float*)d_in[19];
    const float* gate_b   = (const float*)d_in[20];

    const int B = in_sizes[0] / (N * D);   // 8

    float* ws = (float*)d_ws;
    float* EVSUM = ws;             ws += B;
    float* E2    = ws;             ws += B;
    float* SRCT  = ws;             ws += B * 64 * N;
    float* TGT   = ws;             ws += B * N * 64;
    float* VALS  = ws;             ws += B * N * 64;
    float* S2    = ws;             ws += B * N;
    float* T2    = ws;             ws += B * N;
    float* MU    = ws;             ws += B * N;
    float* WAT   = ws;             ws += 64 * H2;
    float* WBT   = ws;             ws += 64 * H2;
    float* WG    = ws;             ws += H2;
    float* WBIAS = ws;             ws += H2;
    float* EVH   = ws;             ws += B * H2;
    float* WsT   = ws;             ws += 64 * 64;
    float* WtT   = ws;             ws += 64 * 64;
    float* WvT   = ws;             ws += 64 * 64;
    float* ABUF  = ws;             ws += B * N * H2;
    float* BPT   = ws;             ws += B * H2 * N;

    hipLaunchKernelGGL(k_prep, dim3(66 + 2 * B + 3), dim3(256), 0, stream,
                       dW1, db1, rW1, rb1, ln_g, ln_b, event, We, be,
                       Ws, Wt, Wv,
                       WAT, WBT, WG, WBIAS, EVH, EVSUM, E2, WsT, WtT, WvT, B);
    hipLaunchKernelGGL(k_projab, dim3(B * 64), dim3(512), 0, stream,
                       x, WsT, bs, WtT, bt, WvT, bv, EVSUM,
                       WAT, WBT, WG, EVH,
                       SRCT, TGT, VALS, S2, T2, MU, ABUF, BPT);
    hipLaunchKernelGGL(k_main, dim3(B * N), dim3(512), 0, stream,
                       SRCT, TGT, VALS, S2, T2, E2, MU, ABUF, BPT, WBIAS,
                       dW2, db2, rW2, rb2, gate_b, (float*)d_out);
}

// Round 6
// 155.814 us; speedup vs baseline: 2.1461x; 1.0642x over previous
//
#include <hip/hip_runtime.h>
#include <math.h>

// Shapes (fixed by the reference setup)
#define D 64
#define E 128
#define H 256
#define N 128
#define H2 512          // drive hidden + resistance hidden concatenated
#define SIXD 384
#define INV_SIXD 0.0026041666666666665f

// ---------------- Workspace layout (floats) ----------------
// EVSUM  [B]
// E2     [B]
// SRCT   [B][64][N]
// TGT    [B][N][64]
// VALS   [B][N][64]
// S2     [B][N]
// T2     [B][N]
// MU     [B][N]
// WAT    [64][512]    coeff of tgt_i (transposed: k-major)
// WBT    [64][512]    coeff of src_j
// WG     [512]
// WBIAS  [512]
// EVH    [B][512]     event contribution to hidden pre-activation
// WsT/WtT/WvT [64][64] transposed projection weights
// ABUF   [B][N][512]
// BPT    [B][512][N]

__device__ __forceinline__ float fast_erff(float x) {
    float ax = fabsf(x);
    float t = __builtin_amdgcn_rcpf(fmaf(0.3275911f, ax, 1.0f));
    float p = t * fmaf(t, fmaf(t, fmaf(t, fmaf(t, 1.061405429f, -1.453152027f),
                               1.421413741f), -0.284496736f), 0.254829592f);
    float r = fmaf(-p, __expf(-ax * ax), 1.0f);
    return copysignf(r, x);
}

__device__ __forceinline__ float fast_gelu(float x) {
    return 0.5f * x * (1.0f + fast_erff(x * 0.70710678118654752f));
}

// K1: all input-only precompute (roles by blockIdx)
__global__ void k_prep(const float* __restrict__ dW1, const float* __restrict__ db1,
                       const float* __restrict__ rW1, const float* __restrict__ rb1,
                       const float* __restrict__ ln_g, const float* __restrict__ ln_b,
                       const float* __restrict__ event, const float* __restrict__ We,
                       const float* __restrict__ be,
                       const float* __restrict__ Ws, const float* __restrict__ Wt,
                       const float* __restrict__ Wv,
                       float* __restrict__ WAT, float* __restrict__ WBT,
                       float* __restrict__ WG, float* __restrict__ WBIAS,
                       float* __restrict__ EVH,
                       float* __restrict__ EVSUM, float* __restrict__ E2,
                       float* __restrict__ WsT, float* __restrict__ WtT,
                       float* __restrict__ WvT, int B) {
    int bid = blockIdx.x;
    int tid = threadIdx.x;       // 0..255
    if (bid < 64) {
        // effective-weight transpose: one d per block, lanes over h (coalesced writes)
        int d = bid;
        float gT = ln_g[d], gS = ln_g[64 + d], gD = ln_g[192 + d];
        for (int h = tid; h < H2; h += 256) {
            const float* W1 = (h < H) ? (dW1 + h * SIXD) : (rW1 + (h - H) * SIXD);
            float w3 = W1[192 + d];
            WAT[d * H2 + h] = W1[d] * gT - w3 * gD;
            WBT[d * H2 + h] = W1[64 + d] * gS + w3 * gD;
        }
    } else if (bid < 66) {
        // WG / WBIAS: one h per thread
        int h = (bid - 64) * 256 + tid;
        const float* W1 = (h < H) ? (dW1 + h * SIXD) : (rW1 + (h - H) * SIXD);
        float b1 = (h < H) ? db1[h] : rb1[h - H];
        float sg = 0.f, sb = 0.f;
        #pragma unroll 8
        for (int m = 0; m < SIXD; ++m) {
            float w = W1[m];
            sg = fmaf(w, ln_g[m], sg);
            sb = fmaf(w, ln_b[m], sb);
        }
        WG[h] = sg;
        WBIAS[h] = sb + b1;
    } else if (bid < 66 + 2 * B) {
        // event projection + EVH
        int t = bid - 66;
        int b = t >> 1, half = t & 1;
        __shared__ float egl[64];
        if (tid < 64) {
            int k = tid;
            float acc = be[k];
            const float* evt = event + b * E;
            const float* w = We + k * E;
            for (int e = 0; e < E; ++e) acc = fmaf(w[e], evt[e], acc);
            egl[k] = acc * ln_g[128 + k];
            if (half == 0) {
                float s = acc, s2 = acc * acc;
                for (int o = 32; o > 0; o >>= 1) {
                    s  += __shfl_down(s, o);
                    s2 += __shfl_down(s2, o);
                }
                if (k == 0) { EVSUM[b] = s; E2[b] = s2; }
            }
        }
        __syncthreads();
        int h = half * 256 + tid;
        const float* W1 = (h < H) ? (dW1 + h * SIXD) : (rW1 + (h - H) * SIXD);
        float acc = 0.f;
        #pragma unroll 8
        for (int k = 0; k < 64; ++k) acc = fmaf(W1[128 + k], egl[k], acc);
        EVH[b * H2 + h] = acc;
    } else {
        // transpose Ws/Wt/Wv -> WsT/WtT/WvT  (WT[k][d] = W[d][k])
        int m = bid - (66 + 2 * B);
        const float* W = (m == 0) ? Ws : (m == 1) ? Wt : Wv;
        float* WT = (m == 0) ? WsT : (m == 1) ? WtT : WvT;
        for (int idx = tid; idx < 64 * 64; idx += 256) {
            int d = idx >> 6, k = idx & 63;
            WT[k * 64 + d] = W[idx];
        }
    }
}

// K2: projections + stats + A,B' hidden precompute. Block = (b, n-pair), 512 threads.
__launch_bounds__(512)
__global__ void k_projab(const float* __restrict__ x,
                         const float* __restrict__ WsT, const float* __restrict__ bs,
                         const float* __restrict__ WtT, const float* __restrict__ bt,
                         const float* __restrict__ WvT, const float* __restrict__ bv,
                         const float* __restrict__ EVSUM,
                         const float* __restrict__ WAT, const float* __restrict__ WBT,
                         const float* __restrict__ WG, const float* __restrict__ EVH,
                         float* __restrict__ SRCT, float* __restrict__ TGT,
                         float* __restrict__ VALS,
                         float* __restrict__ S2, float* __restrict__ T2,
                         float* __restrict__ MU,
                         float* __restrict__ ABUF, float* __restrict__ BPT) {
    int bn2 = blockIdx.x;
    int b = bn2 >> 6;
    int np = bn2 & 63;
    int n0 = np * 2, n1 = n0 + 1;
    int tid = threadIdx.x;       // 0..511
    int q = tid >> 6;            // 0..7
    int d = tid & 63;
    __shared__ float xl0[64], xl1[64], sl0[64], sl1[64], tl0[64], tl1[64];
    __shared__ float mus[2];
    if (q == 0) xl0[d] = x[(b * N + n0) * 64 + d];
    else if (q == 1) xl1[d] = x[(b * N + n1) * 64 + d];
    __syncthreads();

    if (q < 6) {
        int which = (q < 3) ? 0 : 1;             // n0 or n1
        int role = (q < 3) ? q : q - 3;          // 0=src 1=tgt 2=val
        const float* xl = which ? xl1 : xl0;
        int n = which ? n1 : n0;
        const float* WT = (role == 0) ? WsT : (role == 1) ? WtT : WvT;
        float bias = (role == 0) ? bs[d] : (role == 1) ? bt[d] : bv[d];
        float acc = bias;
        #pragma unroll 8
        for (int k = 0; k < 64; ++k) acc = fmaf(WT[k * 64 + d], xl[k], acc);
        if (role == 0) {
            (which ? sl1 : sl0)[d] = acc;
            SRCT[(b * 64 + d) * N + n] = acc;
            float ssum = acc, ssq = acc * acc;
            for (int o = 32; o > 0; o >>= 1) {
                ssum += __shfl_down(ssum, o);
                ssq  += __shfl_down(ssq, o);
            }
            if (d == 0) {
                S2[b * N + n] = ssq;
                float mu = (2.f * ssum + EVSUM[b]) * INV_SIXD;
                MU[b * N + n] = mu;
                mus[which] = mu;
            }
        } else if (role == 1) {
            (which ? tl1 : tl0)[d] = acc;
            TGT[(b * N + n) * 64 + d] = acc;
            float tsq = acc * acc;
            for (int o = 32; o > 0; o >>= 1) tsq += __shfl_down(tsq, o);
            if (d == 0) T2[b * N + n] = tsq;
        } else {
            VALS[(b * N + n) * 64 + d] = acc;
        }
    }
    __syncthreads();

    int h = tid;                 // one h per thread
    float a0 = 0.f, a1 = 0.f, b0 = 0.f, b1 = 0.f;
    #pragma unroll 8
    for (int k = 0; k < 64; ++k) {
        float wa = WAT[k * H2 + h];
        float wb = WBT[k * H2 + h];
        a0 = fmaf(wa, tl0[k], a0);
        a1 = fmaf(wa, tl1[k], a1);
        b0 = fmaf(wb, sl0[k], b0);
        b1 = fmaf(wb, sl1[k], b1);
    }
    float evh = EVH[b * H2 + h];
    float wg = WG[h];
    ABUF[(b * N + n0) * H2 + h] = a0;
    ABUF[(b * N + n1) * H2 + h] = a1;
    BPT[(b * H2 + h) * N + n0] = b0 + evh - mus[0] * wg;
    BPT[(b * H2 + h) * N + n1] = b1 + evh - mus[1] * wg;
}

// K3: main per-pair kernel. Block = (b,i), 512 threads.
__launch_bounds__(512)
__global__ void k_main(const float* __restrict__ SRCT, const float* __restrict__ TGT,
                       const float* __restrict__ VALS,
                       const float* __restrict__ S2, const float* __restrict__ T2,
                       const float* __restrict__ E2, const float* __restrict__ MU,
                       const float* __restrict__ ABUF, const float* __restrict__ BPT,
                       const float* __restrict__ WBIAS,
                       const float* __restrict__ dW2, const float* __restrict__ db2,
                       const float* __restrict__ rW2, const float* __restrict__ rb2,
                       const float* __restrict__ gate_bias,
                       float* __restrict__ out) {
    int bn = blockIdx.x;
    int b = bn >> 7;
    int i = bn & (N - 1);
    int tid = threadIdx.x;       // 0..511
    int q = tid >> 6;            // 0..7  (64-h chunk)
    int p = tid & 63;            // j-pair: j0=2p, j1=2p+1
    __shared__ float4 alwb[H2];                    // {Al, wb, w2, 0} per h
    __shared__ float tl[64], invl[N], dotp[4][N], part[8][N], gl[N];
    __shared__ float accp[8][64], gmp[8];

    // stage
    {
        float al = ABUF[bn * H2 + tid];
        float wb = WBIAS[tid];
        float w2 = (tid < H) ? dW2[tid] : rW2[tid - H];
        alwb[tid] = make_float4(al, wb, w2, 0.f);
        if (tid < 64) tl[tid] = TGT[bn * 64 + tid];
    }
    __syncthreads();

    // phase 1: src_j . tgt_i partials, each (d,j) read exactly once.
    // tid = c*128 + j, c = d-chunk of 16
    {
        int c = tid >> 7;
        int j = tid & (N - 1);
        const float* st = SRCT + b * 64 * N + j;
        float acc = 0.f;
        #pragma unroll
        for (int d = c * 16; d < c * 16 + 16; ++d) acc = fmaf(st[d * N], tl[d], acc);
        dotp[c][j] = acc;
    }
    __syncthreads();

    if (tid < N) {
        int j = tid;
        float dot = dotp[0][j] + dotp[1][j] + dotp[2][j] + dotp[3][j];
        float mu = MU[b * N + j];
        float s2 = S2[b * N + j];
        float ms = (2.f * T2[bn] + 2.f * s2 - 2.f * dot + E2[b]) * INV_SIXD;
        invl[j] = rsqrtf(ms - mu * mu + 1e-5f);
    }
    __syncthreads();

    // phase 2: gelu h-loop. thread (q, p) handles h in [q*64,q*64+64), j = 2p,2p+1
    {
        float inv0 = invl[2 * p];
        float inv1 = invl[2 * p + 1];
        const float* Bp = BPT + (b * H2 + q * 64) * N + 2 * p;
        int hbase = q * 64;
        float acc0 = 0.f, acc1 = 0.f;
        #pragma unroll 8
        for (int hh = 0; hh < 64; ++hh) {
            float2 bp = *(const float2*)&Bp[hh * N];
            float4 aw = alwb[hbase + hh];
            float pre0 = fmaf(inv0, aw.x + bp.x, aw.y);
            float pre1 = fmaf(inv1, aw.x + bp.y, aw.y);
            acc0 = fmaf(fast_gelu(pre0), aw.z, acc0);
            acc1 = fmaf(fast_gelu(pre1), aw.z, acc1);
        }
        part[q][2 * p] = acc0;
        part[q][2 * p + 1] = acc1;
    }
    __syncthreads();

    if (tid < N) {
        int j = tid;
        float drive  = part[0][j] + part[1][j] + part[2][j] + part[3][j] + db2[0];
        float resist = part[4][j] + part[5][j] + part[6][j] + part[7][j] + rb2[0];
        float sp = (resist > 20.f) ? resist : __logf(1.f + __expf(resist));
        float energy = drive / (sp + 1e-6f);
        energy = fminf(fmaxf(energy, -3.f), 3.f);
        float gate = __builtin_amdgcn_rcpf(1.f + __expf(-(energy + gate_bias[0])));
        if (j == i) gate = 0.f;
        gl[j] = gate;
    }
    __syncthreads();

    // aggregation: pc = j-chunk (8 chunks of 16), dd = output dim
    {
        int pc = tid >> 6;
        int dd = tid & 63;
        float va = 0.f, gm = 0.f;
        const float* v = VALS + b * N * 64 + dd;
        #pragma unroll
        for (int jj = pc * 16; jj < pc * 16 + 16; ++jj) {
            float g = gl[jj];
            gm += g;
            va = fmaf(g, v[jj * 64], va);
        }
        accp[pc][dd] = va;
        if (dd == 0) gmp[pc] = gm;
    }
    __syncthreads();

    if (tid < 64) {
        float sum = 0.f, gmsum = 0.f;
        #pragma unroll
        for (int pp = 0; pp < 8; ++pp) {
            sum += accp[pp][tid];
            gmsum += gmp[pp];
        }
        gmsum = fmaxf(gmsum, 1e-6f);
        out[bn * 64 + tid] = sum / gmsum;
    }
}

extern "C" void kernel_launch(void* const* d_in, const int* in_sizes, int n_in,
                              void* d_out, int out_size, void* d_ws, size_t ws_size,
                              hipStream_t stream) {
    const float* x        = (const float*)d_in[0];
    const float* event    = (const float*)d_in[1];
    const float* We       = (const float*)d_in[2];
    const float* be       = (const float*)d_in[3];
    const float* Ws       = (const float*)d_in[4];
    const float* bs       = (const float*)d_in[5];
    const float* Wt       = (const float*)d_in[6];
    const float* bt       = (const float*)d_in[7];
    const float* Wv       = (const float*)d_in[8];
    const float* bv       = (const float*)d_in[9];
    const float* ln_g     = (const float*)d_in[10];
    const float* ln_b     = (const float*)d_in[11];
    const float* dW1      = (const float*)d_in[12];
    const float* db1      = (const float*)d_in[13];
    const float* dW2      = (const float*)d_in[14];
    const float* db2      = (const float*)d_in[15];
    const float* rW1      = (const float*)d_in[16];
    const float* rb1      = (const float*)d_in[17];
    const float* rW2      = (const float*)d_in[18];
    const float* rb2      = (const float*)d_in[19];
    const float* gate_b   = (const float*)d_in[20];

    const int B = in_sizes[0] / (N * D);   // 8

    float* ws = (float*)d_ws;
    float* EVSUM = ws;             ws += B;
    float* E2    = ws;             ws += B;
    float* SRCT  = ws;             ws += B * 64 * N;
    float* TGT   = ws;             ws += B * N * 64;
    float* VALS  = ws;             ws += B * N * 64;
    float* S2    = ws;             ws += B * N;
    float* T2    = ws;             ws += B * N;
    float* MU    = ws;             ws += B * N;
    float* WAT   = ws;             ws += 64 * H2;
    float* WBT   = ws;             ws += 64 * H2;
    float* WG    = ws;             ws += H2;
    float* WBIAS = ws;             ws += H2;
    float* EVH   = ws;             ws += B * H2;
    float* WsT   = ws;             ws += 64 * 64;
    float* WtT   = ws;             ws += 64 * 64;
    float* WvT   = ws;             ws += 64 * 64;
    float* ABUF  = ws;             ws += B * N * H2;
    float* BPT   = ws;             ws += B * H2 * N;

    hipLaunchKernelGGL(k_prep, dim3(66 + 2 * B + 3), dim3(256), 0, stream,
                       dW1, db1, rW1, rb1, ln_g, ln_b, event, We, be,
                       Ws, Wt, Wv,
                       WAT, WBT, WG, WBIAS, EVH, EVSUM, E2, WsT, WtT, WvT, B);
    hipLaunchKernelGGL(k_projab, dim3(B * 64), dim3(512), 0, stream,
                       x, WsT, bs, WtT, bt, WvT, bv, EVSUM,
                       WAT, WBT, WG, EVH,
                       SRCT, TGT, VALS, S2, T2, MU, ABUF, BPT);
    hipLaunchKernelGGL(k_main, dim3(B * N), dim3(512), 0, stream,
                       SRCT, TGT, VALS, S2, T2, E2, MU, ABUF, BPT, WBIAS,
                       dW2, db2, rW2, rb2, gate_b, (float*)d_out);
}